// Round 3
// baseline (100.777 us; speedup 1.0000x reference)
//
#include <hip/hip_runtime.h>

typedef unsigned int uint32;
typedef unsigned short ushort;

typedef __bf16  bf16x8   __attribute__((ext_vector_type(8)));
typedef float   f32x4    __attribute__((ext_vector_type(4)));
typedef ushort  ushort4v __attribute__((ext_vector_type(4)));
typedef float   float4v  __attribute__((ext_vector_type(4)));

#define K_CODES 1024
#define CDIM    64
#define HWALL   4096      // H*W
#define CHW     262144    // CDIM*HWALL

__device__ __forceinline__ ushort f2bf(float f) {
    uint32 u = __builtin_bit_cast(uint32, f);
    u += 0x7FFFu + ((u >> 16) & 1u);   // RNE; inputs are normal floats
    return (ushort)(u >> 16);
}

// Pass 0: codebook fp32 -> bf16 (row-major [k][c]) + negbias[k] = -0.5*||e_k||^2.
// Also zeroes the loss accumulator cell (out[0]).
__global__ __launch_bounds__(256) void prep_kernel(const float* __restrict__ cb,
                                                   ushort* __restrict__ cbb,
                                                   float* __restrict__ negbias,
                                                   float* __restrict__ out) {
    int t = threadIdx.x;
    if (blockIdx.x == 0 && t == 0) out[0] = 0.f;
    int k = blockIdx.x * 4 + (t >> 6);
    int c = t & 63;
    float v = cb[k * 64 + c];
    cbb[k * 64 + c] = f2bf(v);
    float s = v * v;
    #pragma unroll
    for (int d = 1; d < 64; d <<= 1) s += __shfl_xor(s, d, 64);
    if (c == 0) negbias[k] = -0.5f * s;
}

// Main: 1024 blocks x 512 threads (8 waves). Block = 64 z-rows; wave ng owns
// n-tiles [ng*8, ng*8+8) over all 4 m-blocks. 8192 total waves (32/CU requested);
// VGPR cap 85 via launch_bounds -> ~3 blocks/CU resident, phases overlap across
// blocks. Per-block B traffic 128 KB (device 128 MB L2, same as before).
__global__ __launch_bounds__(512, 6) void vq_kernel(const float* __restrict__ z,
                                                    const float* __restrict__ cb,
                                                    const ushort* __restrict__ cbb,
                                                    const float* __restrict__ negbias,
                                                    float* __restrict__ out) {
    // A-tile in MFMA A-layout: [row][k] bf16, row pitch 72 (16B-aligned rows)
    __shared__ __align__(16) ushort Abf[64 * 72];
    __shared__ float partial[8][64];   // packed argmax keys per n-group per row
    __shared__ float loss_acc;

    const int t   = threadIdx.x;
    const int blk = blockIdx.x;
    const int b   = blk >> 6;
    const int hw_base = (blk & 63) << 6;
    const int zoff = b * CHW + hw_base;

    if (t == 0) loss_acc = 0.f;

    const int r  = t & 63;     // z-row within tile (lane index within wave)
    const int cg = t >> 6;     // c-group 0..7 (== wave id)

    // ---- Phase 1: stage z tile (64 rows x 64 c) to LDS as bf16 ----
    // wave reads 64 consecutive floats per c -> coalesced 256B segments
    {
        ushort4v pk0, pk1;
        #pragma unroll
        for (int j = 0; j < 4; ++j) {
            pk0[j] = f2bf(z[zoff + (cg * 8 + j) * HWALL + r]);
            pk1[j] = f2bf(z[zoff + (cg * 8 + 4 + j) * HWALL + r]);
        }
        *(ushort4v*)&Abf[r * 72 + cg * 8]     = pk0;
        *(ushort4v*)&Abf[r * 72 + cg * 8 + 4] = pk1;
    }
    __syncthreads();

    // ---- Phase 2: score GEMM + argmax ----
    const int w  = t >> 6;     // wave id 0..7 == n-group
    const int l  = t & 63;
    const int m  = l & 15;     // A row in m-block / B col in n-tile
    const int q  = l >> 4;     // k-quad

    bf16x8 a[4][2];
    #pragma unroll
    for (int mb = 0; mb < 4; ++mb) {
        int row = mb * 16 + m;
        #pragma unroll
        for (int ks = 0; ks < 2; ++ks)
            a[mb][ks] = *(const bf16x8*)&Abf[row * 72 + ks * 32 + q * 8];
    }

    // packed key = (score bits & ~1023) | (1023 - code_idx): v_max_f32 does argmax
    float best[16];
    #pragma unroll
    for (int i = 0; i < 16; ++i) best[i] = -__builtin_inff();

    const ushort* bbase = cbb + q * 8;
    #pragma unroll
    for (int ntl = 0; ntl < 8; ++ntl) {
        int nt  = w * 8 + ntl;
        int col = (nt << 4) + m;
        bf16x8 b0 = *(const bf16x8*)(bbase + col * 64);
        bf16x8 b1 = *(const bf16x8*)(bbase + col * 64 + 32);
        float  nb = negbias[col];

        uint32 tag = 1023u - (uint32)col;
        f32x4 acc0;
        acc0[0] = nb; acc0[1] = nb; acc0[2] = nb; acc0[3] = nb;
        #pragma unroll
        for (int mb = 0; mb < 4; ++mb) {
            f32x4 acc = __builtin_amdgcn_mfma_f32_16x16x32_bf16(a[mb][0], b0, acc0, 0, 0, 0);
            acc       = __builtin_amdgcn_mfma_f32_16x16x32_bf16(a[mb][1], b1, acc,  0, 0, 0);
            #pragma unroll
            for (int rr = 0; rr < 4; ++rr) {
                uint32 kb = (__builtin_bit_cast(uint32, acc[rr]) & 0xFFFFFC00u) | tag;
                best[mb * 4 + rr] = fmaxf(best[mb * 4 + rr], __builtin_bit_cast(float, kb));
            }
        }
    }

    // cross-lane argmax over the 16 lanes sharing q (cols are lane-distributed)
    #pragma unroll
    for (int i = 0; i < 16; ++i) {
        float v = best[i];
        #pragma unroll
        for (int d = 1; d < 16; d <<= 1) v = fmaxf(v, __shfl_xor(v, d, 64));
        best[i] = v;
    }
    if (m == 0) {     // lanes q=0..3 each own rows mb*16 + q*4 + rr
        #pragma unroll
        for (int mb = 0; mb < 4; ++mb)
            #pragma unroll
            for (int rr = 0; rr < 4; ++rr)
                partial[w][mb * 16 + q * 4 + rr] = best[mb * 4 + rr];
    }
    __syncthreads();

    // ---- Phase 3: combine n-groups, vq_out writeback + loss (zp from LDS bf16) ----
    {
        float km = partial[0][r];
        #pragma unroll
        for (int j = 1; j < 8; ++j) km = fmaxf(km, partial[j][r]);
        int idx = 1023 - (int)(__builtin_bit_cast(uint32, km) & 1023u);

        // this thread covers c = cg*8 .. cg*8+7 for row r
        const float4v* crow = (const float4v*)(cb + idx * 64 + cg * 8);
        float4v e0 = crow[0];
        float4v e1 = crow[1];
        ushort4v zb0 = *(const ushort4v*)&Abf[r * 72 + cg * 8];
        ushort4v zb1 = *(const ushort4v*)&Abf[r * 72 + cg * 8 + 4];

        float lsum = 0.f;
        #pragma unroll
        for (int j = 0; j < 4; ++j) {
            float zp0 = __builtin_bit_cast(float, (uint32)zb0[j] << 16);
            float zp1 = __builtin_bit_cast(float, (uint32)zb1[j] << 16);
            float v0 = e0[j], v1 = e1[j];
            out[1 + zoff + (cg * 8 + j) * HWALL + r]     = v0;  // ST fwd == vq
            out[1 + zoff + (cg * 8 + 4 + j) * HWALL + r] = v1;
            float d0 = v0 - zp0, d1 = v1 - zp1;
            lsum += d0 * d0 + d1 * d1;
        }
        #pragma unroll
        for (int d = 1; d < 64; d <<= 1) lsum += __shfl_xor(lsum, d, 64);
        if (l == 0) atomicAdd(&loss_acc, lsum);
    }
    __syncthreads();
    if (t == 0) atomicAdd(out, loss_acc * (1.25f / 4194304.f));  // (1+BETA)/numel
}

extern "C" void kernel_launch(void* const* d_in, const int* in_sizes, int n_in,
                              void* d_out, int out_size, void* d_ws, size_t ws_size,
                              hipStream_t stream) {
    (void)in_sizes; (void)n_in; (void)out_size; (void)ws_size;
    const float* z  = (const float*)d_in[0];
    const float* cb = (const float*)d_in[1];
    float* out = (float*)d_out;
    ushort* cbb = (ushort*)d_ws;
    float* negbias = (float*)((char*)d_ws + K_CODES * CDIM * sizeof(ushort));

    prep_kernel<<<dim3(256), dim3(256), 0, stream>>>(cb, cbb, negbias, out);
    vq_kernel<<<dim3(1024), dim3(512), 0, stream>>>(z, cb, cbb, negbias, out);
}

// Round 4
// 90.673 us; speedup vs baseline: 1.1114x; 1.1114x over previous
//
#include <hip/hip_runtime.h>

typedef unsigned int uint32;
typedef unsigned short ushort;

typedef __bf16  bf16x8   __attribute__((ext_vector_type(8)));
typedef float   f32x4    __attribute__((ext_vector_type(4)));
typedef ushort  ushort4v __attribute__((ext_vector_type(4)));

#define K_CODES 1024
#define CDIM    64
#define HWALL   4096      // H*W
#define CHW     262144    // CDIM*HWALL
#define ROWS    128       // z-rows per block

__device__ __forceinline__ ushort f2bf(float f) {
    uint32 u = __builtin_bit_cast(uint32, f);
    u += 0x7FFFu + ((u >> 16) & 1u);   // RNE
    return (ushort)(u >> 16);
}

// Pass 0: codebook fp32 -> bf16, written PRE-SWIZZLED: chunk j (8 elems) of code k
// lands at slot (j+k)&7. negbias[k] = -0.5*||e_k||^2. Zeroes loss cell out[0].
__global__ __launch_bounds__(256) void prep_kernel(const float* __restrict__ cb,
                                                   ushort* __restrict__ cbbs,
                                                   float* __restrict__ negbias,
                                                   float* __restrict__ out) {
    int t = threadIdx.x;
    if (blockIdx.x == 0 && t == 0) out[0] = 0.f;
    int k = blockIdx.x * 4 + (t >> 6);
    int c = t & 63;
    float v = cb[k * 64 + c];
    int pos = ((c >> 3) + k) & 7;                    // chunk swizzle
    cbbs[(k << 6) + (pos << 3) + (c & 7)] = f2bf(v);
    float s = v * v;
    #pragma unroll
    for (int d = 1; d < 64; d <<= 1) s += __shfl_xor(s, d, 64);
    if (c == 0) negbias[k] = -0.5f * s;
}

// Main: 512 blocks x 1024 threads (16 waves), 1 block/CU (LDS-bound).
// ENTIRE bf16 codebook staged in LDS (128 KB, chunk-swizzled) -> the hot loop has
// ZERO global loads: B-fragments + negbias come from LDS (ds_read_b128), fixing
// the exposed L2-latency stall of rounds 1-3. Block = 128 z-rows; 16 waves =
// 2 m-groups x 8 n-groups (8 n-tiles each).
__global__ __launch_bounds__(1024, 4) void vq_kernel(const float* __restrict__ z,
                                                     const ushort* __restrict__ cbbs,
                                                     const float* __restrict__ negbias,
                                                     float* __restrict__ out) {
    __shared__ __align__(16) ushort cbL[K_CODES * 64];   // 128 KB swizzled codebook
    __shared__ __align__(16) ushort Abf[ROWS * 72];      // 18 KB A-tile, pitch 72
    __shared__ float nbL[K_CODES];                       // 4 KB
    __shared__ float partial[8][ROWS];                   // 4 KB packed argmax keys
    __shared__ float loss_acc;

    const int t   = threadIdx.x;
    const int blk = blockIdx.x;
    const int b   = blk >> 5;
    const int hw_base = (blk & 31) << 7;
    const int zoff = b * CHW + hw_base;

    if (t == 0) loss_acc = 0.f;

    // ---- Phase 0: codebook + negbias -> LDS (straight coalesced copy; the
    //      swizzle was already applied by prep). 128 B per thread.
    {
        const f32x4* src = (const f32x4*)cbbs;
        f32x4* dst = (f32x4*)cbL;
        #pragma unroll
        for (int i = 0; i < 8; ++i) dst[i * 1024 + t] = src[i * 1024 + t];
        nbL[t] = negbias[t];
    }

    // ---- Phase 1: stage z tile (128 rows x 64 c) to LDS bf16, pitch 72 ----
    const int r  = t & 127;    // z-row (lanes consecutive -> coalesced 256B loads)
    const int cg = t >> 7;     // c-group 0..7
    {
        ushort4v pk0, pk1;
        #pragma unroll
        for (int j = 0; j < 4; ++j) {
            pk0[j] = f2bf(z[zoff + (cg * 8 + j) * HWALL + r]);
            pk1[j] = f2bf(z[zoff + (cg * 8 + 4 + j) * HWALL + r]);
        }
        *(ushort4v*)&Abf[r * 72 + cg * 8]     = pk0;
        *(ushort4v*)&Abf[r * 72 + cg * 8 + 4] = pk1;
    }
    __syncthreads();

    // ---- Phase 2: score GEMM (B from LDS) + argmax ----
    const int w  = t >> 6;     // wave 0..15
    const int l  = t & 63;
    const int mg = w & 1;      // m-group: rows [mg*64, +64)
    const int ng = w >> 1;     // n-group: n-tiles [ng*8, +8)
    const int m  = l & 15;
    const int q  = l >> 4;

    bf16x8 a[4][2];
    #pragma unroll
    for (int mb = 0; mb < 4; ++mb) {
        int row = mg * 64 + mb * 16 + m;
        #pragma unroll
        for (int ks = 0; ks < 2; ++ks)
            a[mb][ks] = *(const bf16x8*)&Abf[row * 72 + ks * 32 + q * 8];
    }

    float best[16];
    #pragma unroll
    for (int i = 0; i < 16; ++i) best[i] = -__builtin_inff();

    #pragma unroll 2
    for (int ntl = 0; ntl < 8; ++ntl) {
        int nt  = ng * 8 + ntl;
        int col = (nt << 4) + m;
        int e0  = (col << 6) + (((q + col) & 7) << 3);   // swizzled chunk q
        bf16x8 b0 = *(const bf16x8*)&cbL[e0];
        bf16x8 b1 = *(const bf16x8*)&cbL[e0 ^ 32];       // chunk q+4 (= pos^4)
        float  nb = nbL[col];

        uint32 tag = 1023u - (uint32)col;
        f32x4 acc0;
        acc0[0] = nb; acc0[1] = nb; acc0[2] = nb; acc0[3] = nb;
        #pragma unroll
        for (int mb = 0; mb < 4; ++mb) {
            f32x4 acc = __builtin_amdgcn_mfma_f32_16x16x32_bf16(a[mb][0], b0, acc0, 0, 0, 0);
            acc       = __builtin_amdgcn_mfma_f32_16x16x32_bf16(a[mb][1], b1, acc,  0, 0, 0);
            #pragma unroll
            for (int rr = 0; rr < 4; ++rr) {
                uint32 kb = (__builtin_bit_cast(uint32, acc[rr]) & 0xFFFFFC00u) | tag;
                best[mb * 4 + rr] = fmaxf(best[mb * 4 + rr], __builtin_bit_cast(float, kb));
            }
        }
    }

    // cross-lane argmax over the 16 lanes sharing q
    #pragma unroll
    for (int i = 0; i < 16; ++i) {
        float v = best[i];
        #pragma unroll
        for (int d = 1; d < 16; d <<= 1) v = fmaxf(v, __shfl_xor(v, d, 64));
        best[i] = v;
    }
    if (m == 0) {
        #pragma unroll
        for (int mb = 0; mb < 4; ++mb)
            #pragma unroll
            for (int rr = 0; rr < 4; ++rr)
                partial[ng][mg * 64 + mb * 16 + q * 4 + rr] = best[mb * 4 + rr];
    }
    __syncthreads();

    // ---- Phase 3: combine n-groups, gather vq from LDS codebook, write + loss ----
    {
        float km = partial[0][r];
        #pragma unroll
        for (int j = 1; j < 8; ++j) km = fmaxf(km, partial[j][r]);
        int idx = 1023 - (int)(__builtin_bit_cast(uint32, km) & 1023u);

        int epos = (idx << 6) + (((cg + idx) & 7) << 3); // this thread's chunk cg
        ushort4v ec0 = *(const ushort4v*)&cbL[epos];
        ushort4v ec1 = *(const ushort4v*)&cbL[epos + 4];
        ushort4v zb0 = *(const ushort4v*)&Abf[r * 72 + cg * 8];
        ushort4v zb1 = *(const ushort4v*)&Abf[r * 72 + cg * 8 + 4];

        float lsum = 0.f;
        #pragma unroll
        for (int j = 0; j < 4; ++j) {
            float v0  = __builtin_bit_cast(float, (uint32)ec0[j] << 16);
            float v1  = __builtin_bit_cast(float, (uint32)ec1[j] << 16);
            float zp0 = __builtin_bit_cast(float, (uint32)zb0[j] << 16);
            float zp1 = __builtin_bit_cast(float, (uint32)zb1[j] << 16);
            out[1 + zoff + (cg * 8 + j) * HWALL + r]     = v0;   // ST fwd == vq
            out[1 + zoff + (cg * 8 + 4 + j) * HWALL + r] = v1;
            float d0 = v0 - zp0, d1 = v1 - zp1;
            lsum += d0 * d0 + d1 * d1;
        }
        #pragma unroll
        for (int d = 1; d < 64; d <<= 1) lsum += __shfl_xor(lsum, d, 64);
        if (l == 0) atomicAdd(&loss_acc, lsum);
    }
    __syncthreads();
    if (t == 0) atomicAdd(out, loss_acc * (1.25f / 4194304.f));  // (1+BETA)/numel
}

extern "C" void kernel_launch(void* const* d_in, const int* in_sizes, int n_in,
                              void* d_out, int out_size, void* d_ws, size_t ws_size,
                              hipStream_t stream) {
    (void)in_sizes; (void)n_in; (void)out_size; (void)ws_size;
    const float* z  = (const float*)d_in[0];
    const float* cb = (const float*)d_in[1];
    float* out = (float*)d_out;
    ushort* cbbs = (ushort*)d_ws;
    float* negbias = (float*)((char*)d_ws + K_CODES * CDIM * sizeof(ushort));

    prep_kernel<<<dim3(256), dim3(256), 0, stream>>>(cb, cbbs, negbias, out);
    vq_kernel<<<dim3(512), dim3(1024), 0, stream>>>(z, cbbs, negbias, out);
}